// Round 10
// baseline (560.804 us; speedup 1.0000x reference)
//
#include <hip/hip_runtime.h>
#include <hip/hip_bf16.h>

#define NN 20000
#define NE 320000
#define NG 16
#define NSCANB 79   // ceil(20000/256)
#define NHISTB 1250 // ceil(320000/256)

// ---------------- pack: edge histogram + layer-1 attention vectors ----------------

__global__ void pack_hist_wlr_kernel(const int* __restrict__ dst, int* __restrict__ indeg,
                                     const float* __restrict__ W1, const float* __restrict__ al1,
                                     const float* __restrict__ ar1, float* __restrict__ wlr) {
  int b = blockIdx.x, t = threadIdx.x;
  if (b < NHISTB) {
    int e = b * 256 + t;
    if (e < NE) atomicAdd(&indeg[dst[e]], 1);
  } else {
    int idx = (b - NHISTB) * 256 + t;  // 768 total
    if (idx >= 768) return;
    int k = idx & 127;
    int j = idx >> 7;  // 0..5
    int h = j % 3;
    const float* av = (j < 3 ? al1 : ar1) + h * 128;
    const float* wrow = W1 + (size_t)k * 384 + h * 128;
    float s = 0.f;
#pragma unroll 4
    for (int d = 0; d < 128; d++) s += wrow[d] * av[d];
    wlr[j * 128 + k] = s;
  }
}

// ---------------- pack: block-local scan of indeg + layer-1 node coefs ----------------

__global__ void pack_scan1_elr_kernel(const int* __restrict__ indeg, int* __restrict__ loc,
                                      int* __restrict__ bsum, const float* __restrict__ x,
                                      const float* __restrict__ wlr, float* __restrict__ el,
                                      float* __restrict__ er) {
  __shared__ int ws[4];
  __shared__ float wl_s[768];
  int b = blockIdx.x, t = threadIdx.x;
  int lane = t & 63, wv = t >> 6;
  if (b < NSCANB) {
    int i = b * 256 + t;
    int v = (i < NN) ? indeg[i] : 0;
    int xx = v;
#pragma unroll
    for (int off = 1; off < 64; off <<= 1) {
      int y = __shfl_up(xx, off);
      if (lane >= off) xx += y;
    }
    if (lane == 63) ws[wv] = xx;
    __syncthreads();
    int add = 0;
    for (int w2 = 0; w2 < wv; w2++) add += ws[w2];
    xx += add;
    if (i < NN) loc[i] = xx - v;
    if (t == 255) bsum[b] = xx;
  } else {
    for (int i = t; i < 768; i += 256) wl_s[i] = wlr[i];
    __syncthreads();
    int w = ((b - NSCANB) * 256 + t) >> 6;
    if (w >= NN) return;
    float v0 = x[(size_t)w * 128 + lane], v1 = x[(size_t)w * 128 + 64 + lane];
    float s[6];
#pragma unroll
    for (int j = 0; j < 6; j++) s[j] = v0 * wl_s[j * 128 + lane] + v1 * wl_s[j * 128 + 64 + lane];
#pragma unroll
    for (int off = 32; off; off >>= 1)
#pragma unroll
      for (int j = 0; j < 6; j++) s[j] += __shfl_down(s[j], off);
    if (lane == 0) {
      el[w * 3 + 0] = s[0]; el[w * 3 + 1] = s[1]; el[w * 3 + 2] = s[2];
      er[w * 3 + 0] = s[3]; er[w * 3 + 1] = s[4]; er[w * 3 + 2] = s[5];
    }
  }
}

__global__ void scan2_kernel(const int* __restrict__ bsum, int* __restrict__ boff,
                             int* __restrict__ rp_end, int nb) {
  int t = threadIdx.x;  // 128
  int lane = t & 63, wv = t >> 6;
  __shared__ int ws[2];
  int v = (t < nb) ? bsum[t] : 0;
  int x = v;
#pragma unroll
  for (int off = 1; off < 64; off <<= 1) {
    int y = __shfl_up(x, off);
    if (lane >= off) x += y;
  }
  if (lane == 63) ws[wv] = x;
  __syncthreads();
  if (wv == 1) x += ws[0];
  if (t < nb) boff[t] = x - v;
  if (t == 127) *rp_end = x;
}

__global__ void pack_scatter_fin_kernel(const int* __restrict__ src, const int* __restrict__ dst,
                                        const int* __restrict__ loc, const int* __restrict__ boff,
                                        int* __restrict__ cursor, int* __restrict__ csr_src,
                                        int* __restrict__ rowptr) {
  int b = blockIdx.x, t = threadIdx.x;
  if (b < NHISTB) {
    int e = b * 256 + t;
    if (e < NE) {
      int d = dst[e];
      int p = atomicAdd(&cursor[d], 1);
      csr_src[loc[d] + boff[d >> 8] + p] = src[e];
    }
  } else {
    int i = (b - NHISTB) * 256 + t;
    if (i < NN) rowptr[i] = loc[i] + boff[i >> 8];
  }
}

// ---------------- layer-1 aggregation in x-space ----------------

__global__ void aggregate_x_kernel(const float* __restrict__ x, const float* __restrict__ el,
                                   const float* __restrict__ er, const int* __restrict__ rowptr,
                                   const int* __restrict__ csr_src, float* __restrict__ aggx) {
  int n = blockIdx.x;
  int t = threadIdx.x;  // 128
  __shared__ float wbuf[3][128];
  __shared__ int sbuf[128];
  __shared__ float red[6];
  __shared__ float4 accbuf[3][4][32];
  int rs = rowptr[n];
  int deg = rowptr[n + 1] - rs;
  float er0 = er[n * 3 + 0], er1 = er[n * 3 + 1], er2 = er[n * 3 + 2];
  float p0 = 0.f, p1 = 0.f, p2 = 0.f;
  int g = t >> 5, dq = t & 31;
  const float* xd = x + dq * 4;
  float4 a0 = make_float4(0, 0, 0, 0), a1 = a0, a2 = a0;
  for (int base = 0; base < deg; base += 128) {
    int cnt = min(128, deg - base);
    if (t < cnt) {
      int s = csr_src[rs + base + t];
      sbuf[t] = s;
      float e0 = el[s * 3 + 0] + er0, e1 = el[s * 3 + 1] + er1, e2 = el[s * 3 + 2] + er2;
      e0 = e0 > 0.f ? e0 : 0.2f * e0;
      e1 = e1 > 0.f ? e1 : 0.2f * e1;
      e2 = e2 > 0.f ? e2 : 0.2f * e2;
      float w0 = __expf(e0), w1 = __expf(e1), w2 = __expf(e2);
      wbuf[0][t] = w0; wbuf[1][t] = w1; wbuf[2][t] = w2;
      p0 += w0; p1 += w1; p2 += w2;
    }
    __syncthreads();
    int j = g;
    for (; j + 4 < cnt; j += 8) {
      int s0 = sbuf[j], s1 = sbuf[j + 4];
      float4 v0 = *(const float4*)(xd + (size_t)s0 * 128);
      float4 v1 = *(const float4*)(xd + (size_t)s1 * 128);
      float w00 = wbuf[0][j], w01 = wbuf[1][j], w02 = wbuf[2][j];
      float w10 = wbuf[0][j + 4], w11 = wbuf[1][j + 4], w12 = wbuf[2][j + 4];
      a0.x += w00 * v0.x + w10 * v1.x; a0.y += w00 * v0.y + w10 * v1.y;
      a0.z += w00 * v0.z + w10 * v1.z; a0.w += w00 * v0.w + w10 * v1.w;
      a1.x += w01 * v0.x + w11 * v1.x; a1.y += w01 * v0.y + w11 * v1.y;
      a1.z += w01 * v0.z + w11 * v1.z; a1.w += w01 * v0.w + w11 * v1.w;
      a2.x += w02 * v0.x + w12 * v1.x; a2.y += w02 * v0.y + w12 * v1.y;
      a2.z += w02 * v0.z + w12 * v1.z; a2.w += w02 * v0.w + w12 * v1.w;
    }
    for (; j < cnt; j += 4) {
      int s = sbuf[j];
      float4 v = *(const float4*)(xd + (size_t)s * 128);
      float w0 = wbuf[0][j], w1 = wbuf[1][j], w2 = wbuf[2][j];
      a0.x += w0 * v.x; a0.y += w0 * v.y; a0.z += w0 * v.z; a0.w += w0 * v.w;
      a1.x += w1 * v.x; a1.y += w1 * v.y; a1.z += w1 * v.z; a1.w += w1 * v.w;
      a2.x += w2 * v.x; a2.y += w2 * v.y; a2.z += w2 * v.z; a2.w += w2 * v.w;
    }
    __syncthreads();
  }
  for (int off = 32; off; off >>= 1) {
    p0 += __shfl_down(p0, off);
    p1 += __shfl_down(p1, off);
    p2 += __shfl_down(p2, off);
  }
  int wv = t >> 6, ln = t & 63;
  if (ln == 0) { red[wv * 3 + 0] = p0; red[wv * 3 + 1] = p1; red[wv * 3 + 2] = p2; }
  accbuf[0][g][dq] = a0;
  accbuf[1][g][dq] = a1;
  accbuf[2][g][dq] = a2;
  __syncthreads();
  if (t < 96) {
    int h = t >> 5, d = t & 31;
    float4 s0 = accbuf[h][0][d], s1 = accbuf[h][1][d], s2 = accbuf[h][2][d], s3 = accbuf[h][3][d];
    float dn = red[h] + red[3 + h];
    float inv = dn > 0.f ? 1.f / dn : 0.f;
    float4 r;
    r.x = (s0.x + s1.x + s2.x + s3.x) * inv;
    r.y = (s0.y + s1.y + s2.y + s3.y) * inv;
    r.z = (s0.z + s1.z + s2.z + s3.z) * inv;
    r.w = (s0.w + s1.w + s2.w + s3.w) * inv;
    *(float4*)&aggx[(size_t)n * 384 + h * 128 + d * 4] = r;
  }
}

// ================= GEMM: 64x128 tile, 128 threads, per-thread 8x8 =================
// As[k][64]: staging writes 2-way-free, A-frag b128 reads pure broadcast.
// Bs[k][128]: B-frag split cols {tn*4, 64+tn*4} -> 2-way-free.
// Per wave-k: 4 b128 (~48 LDS cyc) vs 64 FMA instr (128 VALU cyc) -> VALU-bound.
// LDS 24KB -> 6 blocks/CU. Rows 313*64=20032 > 20000: A OOB reads stay inside ws
// (discarded numerically); stores guarded.
// EL2 (layer-2, gridy=1): epilogue computes el2/er2 = f2 . al2/ar2, plain store.

template <int KT, bool HEADS, bool BIAS_ELU, bool EL2>
__launch_bounds__(128)
__global__ void gemm64_kernel(const float* __restrict__ A, int lda,
                              const float* __restrict__ B, int ldb,
                              float* __restrict__ C, int ldc,
                              const float* __restrict__ bias,
                              const float* __restrict__ al2, const float* __restrict__ ar2,
                              float* __restrict__ el2, float* __restrict__ er2) {
  __shared__ float As[32 * 64];
  __shared__ float Bs[32 * 128];
  int t = threadIdx.x;
  int m0 = blockIdx.x * 64;
  int col0 = blockIdx.y * 128;
  if (HEADS) A += col0;  // head slice of aggx
  int tm = t >> 4, tn = t & 15;
  float acc[8][8];
#pragma unroll
  for (int i = 0; i < 8; i++)
#pragma unroll
    for (int j = 0; j < 8; j++) acc[i][j] = 0.f;

  for (int k0 = 0; k0 < KT; k0 += 32) {
    // stage A 64x32 transposed -> As[k][r]
#pragma unroll
    for (int j = 0; j < 4; j++) {
      int idx = t + j * 128;
      int r = idx & 63, kq = (idx >> 6) * 4;
      float4 v = *(const float4*)&A[(size_t)(m0 + r) * lda + k0 + kq];
      As[(kq + 0) * 64 + r] = v.x;
      As[(kq + 1) * 64 + r] = v.y;
      As[(kq + 2) * 64 + r] = v.z;
      As[(kq + 3) * 64 + r] = v.w;
    }
    // stage B 32x128
#pragma unroll
    for (int j = 0; j < 8; j++) {
      int idx = t + j * 128;
      int kk = idx >> 5, nq = (idx & 31) * 4;
      *(float4*)&Bs[kk * 128 + nq] = *(const float4*)&B[(size_t)(k0 + kk) * ldb + col0 + nq];
    }
    __syncthreads();
#pragma unroll 4
    for (int k = 0; k < 32; k++) {
      float4 fa0 = *(const float4*)&As[k * 64 + tm * 8];
      float4 fa1 = *(const float4*)&As[k * 64 + tm * 8 + 4];
      float4 fb0 = *(const float4*)&Bs[k * 128 + tn * 4];
      float4 fb1 = *(const float4*)&Bs[k * 128 + 64 + tn * 4];
      float af[8] = {fa0.x, fa0.y, fa0.z, fa0.w, fa1.x, fa1.y, fa1.z, fa1.w};
      float bf[8] = {fb0.x, fb0.y, fb0.z, fb0.w, fb1.x, fb1.y, fb1.z, fb1.w};
#pragma unroll
      for (int i = 0; i < 8; i++)
#pragma unroll
        for (int j = 0; j < 8; j++) acc[i][j] += af[i] * bf[j];
    }
    __syncthreads();
  }
  // epilogue
  float bv[8];
  if (BIAS_ELU) {
#pragma unroll
    for (int j = 0; j < 4; j++) {
      bv[j] = bias[col0 + tn * 4 + j];
      bv[4 + j] = bias[col0 + 64 + tn * 4 + j];
    }
  }
#pragma unroll
  for (int i = 0; i < 8; i++) {
    int gm = m0 + tm * 8 + i;
    if (gm < NN) {
      float r[8];
#pragma unroll
      for (int j = 0; j < 8; j++) {
        float v = acc[i][j];
        if (BIAS_ELU) {
          v += bv[j];
          v = v > 0.f ? v : expm1f(v);
        }
        r[j] = v;
      }
      *(float4*)&C[(size_t)gm * ldc + col0 + tn * 4] = make_float4(r[0], r[1], r[2], r[3]);
      *(float4*)&C[(size_t)gm * ldc + col0 + 64 + tn * 4] = make_float4(r[4], r[5], r[6], r[7]);
    }
  }
  if (EL2) {
    float av[8], rv[8];
#pragma unroll
    for (int j = 0; j < 4; j++) {
      av[j] = al2[col0 + tn * 4 + j];   av[4 + j] = al2[col0 + 64 + tn * 4 + j];
      rv[j] = ar2[col0 + tn * 4 + j];   rv[4 + j] = ar2[col0 + 64 + tn * 4 + j];
    }
    __syncthreads();  // done with Bs -> reuse as 64x32 reduction buffer
    float* red = Bs;
#pragma unroll
    for (int i = 0; i < 8; i++) {
      float pe = 0.f, pr = 0.f;
#pragma unroll
      for (int j = 0; j < 8; j++) { pe += acc[i][j] * av[j]; pr += acc[i][j] * rv[j]; }
      red[(tm * 8 + i) * 32 + tn * 2 + 0] = pe;
      red[(tm * 8 + i) * 32 + tn * 2 + 1] = pr;
    }
    __syncthreads();
    if (t < 64) {
      float se = 0.f, sr = 0.f;
#pragma unroll
      for (int q = 0; q < 16; q++) { se += red[t * 32 + 2 * q]; sr += red[t * 32 + 2 * q + 1]; }
      int gm = m0 + t;
      if (gm < NN) { el2[gm] = se; er2[gm] = sr; }  // one block owns each row (gridy==1)
    }
  }
}

// ================= layer-2 aggregation + fused graph-pool atomics =================

__global__ void aggregate1_pool_kernel(const float* __restrict__ f, const float* __restrict__ el,
                                       const float* __restrict__ er, const float* __restrict__ bias,
                                       const int* __restrict__ rowptr, const int* __restrict__ csr_src,
                                       const int* __restrict__ gid, float* __restrict__ gsums) {
  int n = blockIdx.x;
  int t = threadIdx.x;
  __shared__ float wbuf[128];
  __shared__ int sbuf[128];
  __shared__ float red[2];
  __shared__ float4 accbuf[4][32];
  int rs = rowptr[n];
  int deg = rowptr[n + 1] - rs;
  float ern = er[n];
  float psum = 0.f;
  int g = t >> 5;
  int d = (t & 31) * 4;
  const float* fd = f + d;
  float4 acc = make_float4(0.f, 0.f, 0.f, 0.f);
  for (int base = 0; base < deg; base += 128) {
    int cnt = min(128, deg - base);
    if (t < cnt) {
      int s = csr_src[rs + base + t];
      sbuf[t] = s;
      float e = el[s] + ern;
      e = e > 0.f ? e : 0.2f * e;
      float w = __expf(e);
      wbuf[t] = w;
      psum += w;
    }
    __syncthreads();
    int j = g;
    for (; j + 4 < cnt; j += 8) {
      int s0 = sbuf[j], s1 = sbuf[j + 4];
      float4 v0 = *(const float4*)(fd + (size_t)s0 * 128);
      float4 v1 = *(const float4*)(fd + (size_t)s1 * 128);
      float w0 = wbuf[j], w1 = wbuf[j + 4];
      acc.x += w0 * v0.x + w1 * v1.x;
      acc.y += w0 * v0.y + w1 * v1.y;
      acc.z += w0 * v0.z + w1 * v1.z;
      acc.w += w0 * v0.w + w1 * v1.w;
    }
    for (; j < cnt; j += 4) {
      int s = sbuf[j];
      float4 v = *(const float4*)(fd + (size_t)s * 128);
      float w = wbuf[j];
      acc.x += w * v.x; acc.y += w * v.y; acc.z += w * v.z; acc.w += w * v.w;
    }
    __syncthreads();
  }
  for (int off = 32; off; off >>= 1) psum += __shfl_down(psum, off);
  int wv = t >> 6, ln = t & 63;
  if (ln == 0) red[wv] = psum;
  accbuf[g][t & 31] = acc;
  __syncthreads();
  if (t < 32) {
    float4 a0 = accbuf[0][t], a1 = accbuf[1][t], a2 = accbuf[2][t], a3 = accbuf[3][t];
    float dn = red[0] + red[1];
    float inv = dn > 0.f ? 1.f / dn : 0.f;
    const float* bp = bias + t * 4;
    float4 r;
    r.x = (a0.x + a1.x + a2.x + a3.x) * inv + bp[0];
    r.y = (a0.y + a1.y + a2.y + a3.y) * inv + bp[1];
    r.z = (a0.z + a1.z + a2.z + a3.z) * inv + bp[2];
    r.w = (a0.w + a1.w + a2.w + a3.w) * inv + bp[3];
    float* gp = &gsums[gid[n] * 128 + t * 4];
    atomicAdd(&gp[0], r.x); atomicAdd(&gp[1], r.y);
    atomicAdd(&gp[2], r.z); atomicAdd(&gp[3], r.w);
  }
}

// ================= final: mean + linear head + relu =================

__global__ void pool_final_kernel(const float* __restrict__ sums, const int* __restrict__ gid,
                                  const float* __restrict__ linW, const float* __restrict__ linb,
                                  float* __restrict__ out, int N) {
  int g = blockIdx.x;
  int tid = threadIdx.x;
  int lo0 = 0, hi0 = N;
  while (lo0 < hi0) { int m = (lo0 + hi0) >> 1; if (gid[m] < g) lo0 = m + 1; else hi0 = m; }
  int lo1 = lo0, hi1 = N;
  while (lo1 < hi1) { int m = (lo1 + hi1) >> 1; if (gid[m] < g + 1) lo1 = m + 1; else hi1 = m; }
  int cnt = lo1 - lo0;
  float hg = sums[g * 128 + tid] / (float)(cnt > 0 ? cnt : 1);
  __shared__ float hgs[128];
  hgs[tid] = hg;
  __syncthreads();
  float o = linb[tid];
#pragma unroll 4
  for (int dd = 0; dd < 128; dd++) o += hgs[dd] * linW[dd * 128 + tid];
  out[g * 128 + tid] = fmaxf(o, 0.f);
}

// ================= launch =================

extern "C" void kernel_launch(void* const* d_in, const int* in_sizes, int n_in,
                              void* d_out, int out_size, void* d_ws, size_t ws_size,
                              hipStream_t stream) {
  const float* x    = (const float*)d_in[0];
  const int*   src  = (const int*)d_in[1];
  const int*   dst  = (const int*)d_in[2];
  const int*   gid  = (const int*)d_in[3];
  const float* W1   = (const float*)d_in[4];
  const float* al1  = (const float*)d_in[5];
  const float* ar1  = (const float*)d_in[6];
  const float* b1   = (const float*)d_in[7];
  const float* W2   = (const float*)d_in[8];
  const float* al2  = (const float*)d_in[9];
  const float* ar2  = (const float*)d_in[10];
  const float* b2   = (const float*)d_in[11];
  const float* linW = (const float*)d_in[12];
  const float* linb = (const float*)d_in[13];
  float* out = (float*)d_out;

  char* ws = (char*)d_ws;
  size_t off = 0;
  auto alloc = [&](size_t bytes) -> void* {
    void* p = ws + off;
    off += (bytes + 255) & ~(size_t)255;
    return p;
  };
  float* aggx    = (float*)alloc((size_t)NN * 384 * 4);
  float* h1      = (float*)alloc((size_t)NN * 384 * 4);
  float* f2      = (float*)alloc((size_t)NN * 128 * 4);
  float* guard   = (float*)alloc((size_t)64 * 384 * 4);  // OOB-read landing zone for gemm A
  float* el1     = (float*)alloc((size_t)NN * 3 * 4);
  float* er1     = (float*)alloc((size_t)NN * 3 * 4);
  float* el2     = (float*)alloc((size_t)NN * 4);
  float* er2     = (float*)alloc((size_t)NN * 4);
  float* wlr     = (float*)alloc((size_t)768 * 4);
  int*   loc     = (int*)alloc((size_t)NN * 4);
  int*   rowptr  = (int*)alloc((size_t)(NN + 1) * 4);
  int*   csr_src = (int*)alloc((size_t)NE * 4);
  int*   bsum    = (int*)alloc((size_t)NSCANB * 4);
  int*   boff    = (int*)alloc((size_t)NSCANB * 4);
  // zero-initialized region (single memset): indeg, cursor, gsums
  int*   indeg   = (int*)alloc((size_t)NN * 4);
  int*   cursor  = (int*)alloc((size_t)NN * 4);
  float* gsums   = (float*)alloc((size_t)NG * 128 * 4);
  (void)ws_size; (void)guard;
  size_t zbytes = (char*)(gsums + NG * 128) - (char*)indeg;
  hipMemsetAsync(indeg, 0, zbytes, stream);

  // CSR build + layer-1 attention coefs (packed)
  pack_hist_wlr_kernel<<<NHISTB + 3, 256, 0, stream>>>(dst, indeg, W1, al1, ar1, wlr);
  pack_scan1_elr_kernel<<<NSCANB + 5000, 256, 0, stream>>>(indeg, loc, bsum, x, wlr, el1, er1);
  scan2_kernel<<<1, 128, 0, stream>>>(bsum, boff, rowptr + NN, NSCANB);
  pack_scatter_fin_kernel<<<NHISTB + NSCANB, 256, 0, stream>>>(src, dst, loc, boff, cursor,
                                                               csr_src, rowptr);

  // Layer 1 (x-space): aggregate x -> per-head GEMM with bias+ELU
  aggregate_x_kernel<<<NN, 128, 0, stream>>>(x, el1, er1, rowptr, csr_src, aggx);
  gemm64_kernel<128, true, true, false><<<dim3(313, 3), 128, 0, stream>>>(
      aggx, 384, W1, 384, h1, 384, b1, nullptr, nullptr, nullptr, nullptr);

  // Layer 2: f2 = h1 @ W2 (fused el2/er2 epilogue); aggregate(+b2) + fused pool
  gemm64_kernel<384, false, false, true><<<dim3(313, 1), 128, 0, stream>>>(
      h1, 384, W2, 128, f2, 128, nullptr, al2, ar2, el2, er2);
  aggregate1_pool_kernel<<<NN, 128, 0, stream>>>(f2, el2, er2, b2, rowptr, csr_src, gid, gsums);

  // mean + linear head + relu
  pool_final_kernel<<<NG, 128, 0, stream>>>(gsums, gid, linW, linb, out, NN);
}

// Round 11
// 328.319 us; speedup vs baseline: 1.7081x; 1.7081x over previous
//
#include <hip/hip_runtime.h>
#include <hip/hip_bf16.h>

#define NN 20000
#define NE 320000
#define NG 16
#define PSPLIT 32
#define NSCANB 79   // ceil(20000/256)
#define NHISTB 1250 // ceil(320000/256)

// ---------------- pack: edge histogram + layer-1 attention vectors ----------------

__global__ void pack_hist_wlr_kernel(const int* __restrict__ dst, int* __restrict__ indeg,
                                     const float* __restrict__ W1, const float* __restrict__ al1,
                                     const float* __restrict__ ar1, float* __restrict__ wlr) {
  int b = blockIdx.x, t = threadIdx.x;
  if (b < NHISTB) {
    int e = b * 256 + t;
    if (e < NE) atomicAdd(&indeg[dst[e]], 1);
  } else {
    int idx = (b - NHISTB) * 256 + t;  // 768 total
    if (idx >= 768) return;
    int k = idx & 127;
    int j = idx >> 7;  // 0..5
    int h = j % 3;
    const float* av = (j < 3 ? al1 : ar1) + h * 128;
    const float* wrow = W1 + (size_t)k * 384 + h * 128;
    float s = 0.f;
#pragma unroll 4
    for (int d = 0; d < 128; d++) s += wrow[d] * av[d];
    wlr[j * 128 + k] = s;
  }
}

// ---------------- pack: block-local scan of indeg + layer-1 node coefs ----------------

__global__ void pack_scan1_elr_kernel(const int* __restrict__ indeg, int* __restrict__ loc,
                                      int* __restrict__ bsum, const float* __restrict__ x,
                                      const float* __restrict__ wlr, float* __restrict__ el,
                                      float* __restrict__ er) {
  __shared__ int ws[4];
  __shared__ float wl_s[768];
  int b = blockIdx.x, t = threadIdx.x;
  int lane = t & 63, wv = t >> 6;
  if (b < NSCANB) {
    int i = b * 256 + t;
    int v = (i < NN) ? indeg[i] : 0;
    int xx = v;
#pragma unroll
    for (int off = 1; off < 64; off <<= 1) {
      int y = __shfl_up(xx, off);
      if (lane >= off) xx += y;
    }
    if (lane == 63) ws[wv] = xx;
    __syncthreads();
    int add = 0;
    for (int w2 = 0; w2 < wv; w2++) add += ws[w2];
    xx += add;
    if (i < NN) loc[i] = xx - v;
    if (t == 255) bsum[b] = xx;
  } else {
    for (int i = t; i < 768; i += 256) wl_s[i] = wlr[i];
    __syncthreads();
    int w = ((b - NSCANB) * 256 + t) >> 6;
    if (w >= NN) return;
    float v0 = x[(size_t)w * 128 + lane], v1 = x[(size_t)w * 128 + 64 + lane];
    float s[6];
#pragma unroll
    for (int j = 0; j < 6; j++) s[j] = v0 * wl_s[j * 128 + lane] + v1 * wl_s[j * 128 + 64 + lane];
#pragma unroll
    for (int off = 32; off; off >>= 1)
#pragma unroll
      for (int j = 0; j < 6; j++) s[j] += __shfl_down(s[j], off);
    if (lane == 0) {
      el[w * 3 + 0] = s[0]; el[w * 3 + 1] = s[1]; el[w * 3 + 2] = s[2];
      er[w * 3 + 0] = s[3]; er[w * 3 + 1] = s[4]; er[w * 3 + 2] = s[5];
    }
  }
}

__global__ void scan2_kernel(const int* __restrict__ bsum, int* __restrict__ boff,
                             int* __restrict__ rp_end, int nb) {
  int t = threadIdx.x;  // 128
  int lane = t & 63, wv = t >> 6;
  __shared__ int ws[2];
  int v = (t < nb) ? bsum[t] : 0;
  int x = v;
#pragma unroll
  for (int off = 1; off < 64; off <<= 1) {
    int y = __shfl_up(x, off);
    if (lane >= off) x += y;
  }
  if (lane == 63) ws[wv] = x;
  __syncthreads();
  if (wv == 1) x += ws[0];
  if (t < nb) boff[t] = x - v;
  if (t == 127) *rp_end = x;
}

__global__ void pack_scatter_fin_kernel(const int* __restrict__ src, const int* __restrict__ dst,
                                        const int* __restrict__ loc, const int* __restrict__ boff,
                                        int* __restrict__ cursor, int* __restrict__ csr_src,
                                        int* __restrict__ rowptr) {
  int b = blockIdx.x, t = threadIdx.x;
  if (b < NHISTB) {
    int e = b * 256 + t;
    if (e < NE) {
      int d = dst[e];
      int p = atomicAdd(&cursor[d], 1);
      csr_src[loc[d] + boff[d >> 8] + p] = src[e];
    }
  } else {
    int i = (b - NHISTB) * 256 + t;
    if (i < NN) rowptr[i] = loc[i] + boff[i >> 8];
  }
}

// ---------------- layer-1 aggregation in x-space ----------------

__global__ void aggregate_x_kernel(const float* __restrict__ x, const float* __restrict__ el,
                                   const float* __restrict__ er, const int* __restrict__ rowptr,
                                   const int* __restrict__ csr_src, float* __restrict__ aggx) {
  int n = blockIdx.x;
  int t = threadIdx.x;  // 128
  __shared__ float wbuf[3][128];
  __shared__ int sbuf[128];
  __shared__ float red[6];
  __shared__ float4 accbuf[3][4][32];
  int rs = rowptr[n];
  int deg = rowptr[n + 1] - rs;
  float er0 = er[n * 3 + 0], er1 = er[n * 3 + 1], er2 = er[n * 3 + 2];
  float p0 = 0.f, p1 = 0.f, p2 = 0.f;
  int g = t >> 5, dq = t & 31;
  const float* xd = x + dq * 4;
  float4 a0 = make_float4(0, 0, 0, 0), a1 = a0, a2 = a0;
  for (int base = 0; base < deg; base += 128) {
    int cnt = min(128, deg - base);
    if (t < cnt) {
      int s = csr_src[rs + base + t];
      sbuf[t] = s;
      float e0 = el[s * 3 + 0] + er0, e1 = el[s * 3 + 1] + er1, e2 = el[s * 3 + 2] + er2;
      e0 = e0 > 0.f ? e0 : 0.2f * e0;
      e1 = e1 > 0.f ? e1 : 0.2f * e1;
      e2 = e2 > 0.f ? e2 : 0.2f * e2;
      float w0 = __expf(e0), w1 = __expf(e1), w2 = __expf(e2);
      wbuf[0][t] = w0; wbuf[1][t] = w1; wbuf[2][t] = w2;
      p0 += w0; p1 += w1; p2 += w2;
    }
    __syncthreads();
    int j = g;
    for (; j + 4 < cnt; j += 8) {
      int s0 = sbuf[j], s1 = sbuf[j + 4];
      float4 v0 = *(const float4*)(xd + (size_t)s0 * 128);
      float4 v1 = *(const float4*)(xd + (size_t)s1 * 128);
      float w00 = wbuf[0][j], w01 = wbuf[1][j], w02 = wbuf[2][j];
      float w10 = wbuf[0][j + 4], w11 = wbuf[1][j + 4], w12 = wbuf[2][j + 4];
      a0.x += w00 * v0.x + w10 * v1.x; a0.y += w00 * v0.y + w10 * v1.y;
      a0.z += w00 * v0.z + w10 * v1.z; a0.w += w00 * v0.w + w10 * v1.w;
      a1.x += w01 * v0.x + w11 * v1.x; a1.y += w01 * v0.y + w11 * v1.y;
      a1.z += w01 * v0.z + w11 * v1.z; a1.w += w01 * v0.w + w11 * v1.w;
      a2.x += w02 * v0.x + w12 * v1.x; a2.y += w02 * v0.y + w12 * v1.y;
      a2.z += w02 * v0.z + w12 * v1.z; a2.w += w02 * v0.w + w12 * v1.w;
    }
    for (; j < cnt; j += 4) {
      int s = sbuf[j];
      float4 v = *(const float4*)(xd + (size_t)s * 128);
      float w0 = wbuf[0][j], w1 = wbuf[1][j], w2 = wbuf[2][j];
      a0.x += w0 * v.x; a0.y += w0 * v.y; a0.z += w0 * v.z; a0.w += w0 * v.w;
      a1.x += w1 * v.x; a1.y += w1 * v.y; a1.z += w1 * v.z; a1.w += w1 * v.w;
      a2.x += w2 * v.x; a2.y += w2 * v.y; a2.z += w2 * v.z; a2.w += w2 * v.w;
    }
    __syncthreads();
  }
  for (int off = 32; off; off >>= 1) {
    p0 += __shfl_down(p0, off);
    p1 += __shfl_down(p1, off);
    p2 += __shfl_down(p2, off);
  }
  int wv = t >> 6, ln = t & 63;
  if (ln == 0) { red[wv * 3 + 0] = p0; red[wv * 3 + 1] = p1; red[wv * 3 + 2] = p2; }
  accbuf[0][g][dq] = a0;
  accbuf[1][g][dq] = a1;
  accbuf[2][g][dq] = a2;
  __syncthreads();
  if (t < 96) {
    int h = t >> 5, d = t & 31;
    float4 s0 = accbuf[h][0][d], s1 = accbuf[h][1][d], s2 = accbuf[h][2][d], s3 = accbuf[h][3][d];
    float dn = red[h] + red[3 + h];
    float inv = dn > 0.f ? 1.f / dn : 0.f;
    float4 r;
    r.x = (s0.x + s1.x + s2.x + s3.x) * inv;
    r.y = (s0.y + s1.y + s2.y + s3.y) * inv;
    r.z = (s0.z + s1.z + s2.z + s3.z) * inv;
    r.w = (s0.w + s1.w + s2.w + s3.w) * inv;
    *(float4*)&aggx[(size_t)n * 384 + h * 128 + d * 4] = r;
  }
}

// ================= GEMM: 64x128 tile, 128 threads, per-thread 8x8 =================
// As[k][64]: staging writes 2-way-free, A-frag b128 reads pure broadcast.
// Bs[k][128]: B-frag split cols {tn*4, 64+tn*4} -> 2-way-free.
// Per wave-k: 4 b128 (~48 LDS cyc) vs 64 FMA instr (128 VALU cyc) -> VALU-bound.
// LDS 24KB -> 6 blocks/CU. Rows 313*64=20032 > 20000: A OOB reads land in the
// guard buffer right after f2 in ws (discarded numerically); stores guarded.
// EL2 (layer-2, gridy=1): epilogue computes el2/er2 = f2 . al2/ar2, plain store.

template <int KT, bool HEADS, bool BIAS_ELU, bool EL2>
__launch_bounds__(128)
__global__ void gemm64_kernel(const float* __restrict__ A, int lda,
                              const float* __restrict__ B, int ldb,
                              float* __restrict__ C, int ldc,
                              const float* __restrict__ bias,
                              const float* __restrict__ al2, const float* __restrict__ ar2,
                              float* __restrict__ el2, float* __restrict__ er2) {
  __shared__ float As[32 * 64];
  __shared__ float Bs[32 * 128];
  int t = threadIdx.x;
  int m0 = blockIdx.x * 64;
  int col0 = blockIdx.y * 128;
  if (HEADS) A += col0;  // head slice of aggx
  int tm = t >> 4, tn = t & 15;
  float acc[8][8];
#pragma unroll
  for (int i = 0; i < 8; i++)
#pragma unroll
    for (int j = 0; j < 8; j++) acc[i][j] = 0.f;

  for (int k0 = 0; k0 < KT; k0 += 32) {
    // stage A 64x32 transposed -> As[k][r]
#pragma unroll
    for (int j = 0; j < 4; j++) {
      int idx = t + j * 128;
      int r = idx & 63, kq = (idx >> 6) * 4;
      float4 v = *(const float4*)&A[(size_t)(m0 + r) * lda + k0 + kq];
      As[(kq + 0) * 64 + r] = v.x;
      As[(kq + 1) * 64 + r] = v.y;
      As[(kq + 2) * 64 + r] = v.z;
      As[(kq + 3) * 64 + r] = v.w;
    }
    // stage B 32x128
#pragma unroll
    for (int j = 0; j < 8; j++) {
      int idx = t + j * 128;
      int kk = idx >> 5, nq = (idx & 31) * 4;
      *(float4*)&Bs[kk * 128 + nq] = *(const float4*)&B[(size_t)(k0 + kk) * ldb + col0 + nq];
    }
    __syncthreads();
#pragma unroll 4
    for (int k = 0; k < 32; k++) {
      float4 fa0 = *(const float4*)&As[k * 64 + tm * 8];
      float4 fa1 = *(const float4*)&As[k * 64 + tm * 8 + 4];
      float4 fb0 = *(const float4*)&Bs[k * 128 + tn * 4];
      float4 fb1 = *(const float4*)&Bs[k * 128 + 64 + tn * 4];
      float af[8] = {fa0.x, fa0.y, fa0.z, fa0.w, fa1.x, fa1.y, fa1.z, fa1.w};
      float bf[8] = {fb0.x, fb0.y, fb0.z, fb0.w, fb1.x, fb1.y, fb1.z, fb1.w};
#pragma unroll
      for (int i = 0; i < 8; i++)
#pragma unroll
        for (int j = 0; j < 8; j++) acc[i][j] += af[i] * bf[j];
    }
    __syncthreads();
  }
  // epilogue
  float bv[8];
  if (BIAS_ELU) {
#pragma unroll
    for (int j = 0; j < 4; j++) {
      bv[j] = bias[col0 + tn * 4 + j];
      bv[4 + j] = bias[col0 + 64 + tn * 4 + j];
    }
  }
#pragma unroll
  for (int i = 0; i < 8; i++) {
    int gm = m0 + tm * 8 + i;
    if (gm < NN) {
      float r[8];
#pragma unroll
      for (int j = 0; j < 8; j++) {
        float v = acc[i][j];
        if (BIAS_ELU) {
          v += bv[j];
          v = v > 0.f ? v : expm1f(v);
        }
        r[j] = v;
      }
      *(float4*)&C[(size_t)gm * ldc + col0 + tn * 4] = make_float4(r[0], r[1], r[2], r[3]);
      *(float4*)&C[(size_t)gm * ldc + col0 + 64 + tn * 4] = make_float4(r[4], r[5], r[6], r[7]);
    }
  }
  if (EL2) {
    float av[8], rv[8];
#pragma unroll
    for (int j = 0; j < 4; j++) {
      av[j] = al2[col0 + tn * 4 + j];   av[4 + j] = al2[col0 + 64 + tn * 4 + j];
      rv[j] = ar2[col0 + tn * 4 + j];   rv[4 + j] = ar2[col0 + 64 + tn * 4 + j];
    }
    __syncthreads();  // done with Bs -> reuse as 64x32 reduction buffer
    float* red = Bs;
#pragma unroll
    for (int i = 0; i < 8; i++) {
      float pe = 0.f, pr = 0.f;
#pragma unroll
      for (int j = 0; j < 8; j++) { pe += acc[i][j] * av[j]; pr += acc[i][j] * rv[j]; }
      red[(tm * 8 + i) * 32 + tn * 2 + 0] = pe;
      red[(tm * 8 + i) * 32 + tn * 2 + 1] = pr;
    }
    __syncthreads();
    if (t < 64) {
      float se = 0.f, sr = 0.f;
#pragma unroll
      for (int q = 0; q < 16; q++) { se += red[t * 32 + 2 * q]; sr += red[t * 32 + 2 * q + 1]; }
      int gm = m0 + t;
      if (gm < NN) { el2[gm] = se; er2[gm] = sr; }  // one block owns each row (gridy==1)
    }
  }
}

// ================= layer-2 aggregation (writes h2; NO pool atomics) =================

__global__ void aggregate1_kernel(const float* __restrict__ f, const float* __restrict__ el,
                                  const float* __restrict__ er, const float* __restrict__ bias,
                                  const int* __restrict__ rowptr, const int* __restrict__ csr_src,
                                  float* __restrict__ out) {
  int n = blockIdx.x;
  int t = threadIdx.x;
  __shared__ float wbuf[128];
  __shared__ int sbuf[128];
  __shared__ float red[2];
  __shared__ float4 accbuf[4][32];
  int rs = rowptr[n];
  int deg = rowptr[n + 1] - rs;
  float ern = er[n];
  float psum = 0.f;
  int g = t >> 5;
  int d = (t & 31) * 4;
  const float* fd = f + d;
  float4 acc = make_float4(0.f, 0.f, 0.f, 0.f);
  for (int base = 0; base < deg; base += 128) {
    int cnt = min(128, deg - base);
    if (t < cnt) {
      int s = csr_src[rs + base + t];
      sbuf[t] = s;
      float e = el[s] + ern;
      e = e > 0.f ? e : 0.2f * e;
      float w = __expf(e);
      wbuf[t] = w;
      psum += w;
    }
    __syncthreads();
    int j = g;
    for (; j + 4 < cnt; j += 8) {
      int s0 = sbuf[j], s1 = sbuf[j + 4];
      float4 v0 = *(const float4*)(fd + (size_t)s0 * 128);
      float4 v1 = *(const float4*)(fd + (size_t)s1 * 128);
      float w0 = wbuf[j], w1 = wbuf[j + 4];
      acc.x += w0 * v0.x + w1 * v1.x;
      acc.y += w0 * v0.y + w1 * v1.y;
      acc.z += w0 * v0.z + w1 * v1.z;
      acc.w += w0 * v0.w + w1 * v1.w;
    }
    for (; j < cnt; j += 4) {
      int s = sbuf[j];
      float4 v = *(const float4*)(fd + (size_t)s * 128);
      float w = wbuf[j];
      acc.x += w * v.x; acc.y += w * v.y; acc.z += w * v.z; acc.w += w * v.w;
    }
    __syncthreads();
  }
  for (int off = 32; off; off >>= 1) psum += __shfl_down(psum, off);
  int wv = t >> 6, ln = t & 63;
  if (ln == 0) red[wv] = psum;
  accbuf[g][t & 31] = acc;
  __syncthreads();
  if (t < 32) {
    float4 a0 = accbuf[0][t], a1 = accbuf[1][t], a2 = accbuf[2][t], a3 = accbuf[3][t];
    float dn = red[0] + red[1];
    float inv = dn > 0.f ? 1.f / dn : 0.f;
    const float* bp = bias + t * 4;
    float4 r;
    r.x = (a0.x + a1.x + a2.x + a3.x) * inv + bp[0];
    r.y = (a0.y + a1.y + a2.y + a3.y) * inv + bp[1];
    r.z = (a0.z + a1.z + a2.z + a3.z) * inv + bp[2];
    r.w = (a0.w + a1.w + a2.w + a3.w) * inv + bp[3];
    *(float4*)&out[(size_t)n * 128 + t * 4] = r;
  }
}

// ================= mean-pool: 2-stage (32 atomics/cell, proven) =================

__global__ void pool_partial_kernel(const float* __restrict__ h2, const int* __restrict__ gid,
                                    float* __restrict__ sums, int N) {
  int g = blockIdx.x / PSPLIT;
  int sp = blockIdx.x % PSPLIT;
  int tid = threadIdx.x;
  int lo0 = 0, hi0 = N;
  while (lo0 < hi0) { int m = (lo0 + hi0) >> 1; if (gid[m] < g) lo0 = m + 1; else hi0 = m; }
  int lo1 = lo0, hi1 = N;
  while (lo1 < hi1) { int m = (lo1 + hi1) >> 1; if (gid[m] < g + 1) lo1 = m + 1; else hi1 = m; }
  float a0 = 0.f, a1 = 0.f, a2 = 0.f, a3 = 0.f;
  int n = lo0 + sp;
  for (; n + 3 * PSPLIT < lo1; n += 4 * PSPLIT) {
    a0 += h2[(size_t)n * 128 + tid];
    a1 += h2[(size_t)(n + PSPLIT) * 128 + tid];
    a2 += h2[(size_t)(n + 2 * PSPLIT) * 128 + tid];
    a3 += h2[(size_t)(n + 3 * PSPLIT) * 128 + tid];
  }
  for (; n < lo1; n += PSPLIT) a0 += h2[(size_t)n * 128 + tid];
  float acc = (a0 + a1) + (a2 + a3);
  atomicAdd(&sums[g * 128 + tid], acc);
}

__global__ void pool_final_kernel(const float* __restrict__ sums, const int* __restrict__ gid,
                                  const float* __restrict__ linW, const float* __restrict__ linb,
                                  float* __restrict__ out, int N) {
  int g = blockIdx.x;
  int tid = threadIdx.x;
  int lo0 = 0, hi0 = N;
  while (lo0 < hi0) { int m = (lo0 + hi0) >> 1; if (gid[m] < g) lo0 = m + 1; else hi0 = m; }
  int lo1 = lo0, hi1 = N;
  while (lo1 < hi1) { int m = (lo1 + hi1) >> 1; if (gid[m] < g + 1) lo1 = m + 1; else hi1 = m; }
  int cnt = lo1 - lo0;
  float hg = sums[g * 128 + tid] / (float)(cnt > 0 ? cnt : 1);
  __shared__ float hgs[128];
  hgs[tid] = hg;
  __syncthreads();
  float o = linb[tid];
#pragma unroll 4
  for (int dd = 0; dd < 128; dd++) o += hgs[dd] * linW[dd * 128 + tid];
  out[g * 128 + tid] = fmaxf(o, 0.f);
}

// ================= launch =================

extern "C" void kernel_launch(void* const* d_in, const int* in_sizes, int n_in,
                              void* d_out, int out_size, void* d_ws, size_t ws_size,
                              hipStream_t stream) {
  const float* x    = (const float*)d_in[0];
  const int*   src  = (const int*)d_in[1];
  const int*   dst  = (const int*)d_in[2];
  const int*   gid  = (const int*)d_in[3];
  const float* W1   = (const float*)d_in[4];
  const float* al1  = (const float*)d_in[5];
  const float* ar1  = (const float*)d_in[6];
  const float* b1   = (const float*)d_in[7];
  const float* W2   = (const float*)d_in[8];
  const float* al2  = (const float*)d_in[9];
  const float* ar2  = (const float*)d_in[10];
  const float* b2   = (const float*)d_in[11];
  const float* linW = (const float*)d_in[12];
  const float* linb = (const float*)d_in[13];
  float* out = (float*)d_out;

  char* ws = (char*)d_ws;
  size_t off = 0;
  auto alloc = [&](size_t bytes) -> void* {
    void* p = ws + off;
    off += (bytes + 255) & ~(size_t)255;
    return p;
  };
  float* aggx    = (float*)alloc((size_t)NN * 384 * 4);
  float* h1      = (float*)alloc((size_t)NN * 384 * 4);
  float* f2      = (float*)alloc((size_t)NN * 128 * 4);
  float* guard   = (float*)alloc((size_t)64 * 384 * 4);  // OOB-read landing zone for gemm A
  float* h2      = (float*)alloc((size_t)NN * 128 * 4);
  float* el1     = (float*)alloc((size_t)NN * 3 * 4);
  float* er1     = (float*)alloc((size_t)NN * 3 * 4);
  float* el2     = (float*)alloc((size_t)NN * 4);
  float* er2     = (float*)alloc((size_t)NN * 4);
  float* wlr     = (float*)alloc((size_t)768 * 4);
  int*   loc     = (int*)alloc((size_t)NN * 4);
  int*   rowptr  = (int*)alloc((size_t)(NN + 1) * 4);
  int*   csr_src = (int*)alloc((size_t)NE * 4);
  int*   bsum    = (int*)alloc((size_t)NSCANB * 4);
  int*   boff    = (int*)alloc((size_t)NSCANB * 4);
  // zero-initialized region (single memset): indeg, cursor, gsums
  int*   indeg   = (int*)alloc((size_t)NN * 4);
  int*   cursor  = (int*)alloc((size_t)NN * 4);
  float* gsums   = (float*)alloc((size_t)NG * 128 * 4);
  (void)ws_size; (void)guard;
  size_t zbytes = (char*)(gsums + NG * 128) - (char*)indeg;
  hipMemsetAsync(indeg, 0, zbytes, stream);

  // CSR build + layer-1 attention coefs (packed)
  pack_hist_wlr_kernel<<<NHISTB + 3, 256, 0, stream>>>(dst, indeg, W1, al1, ar1, wlr);
  pack_scan1_elr_kernel<<<NSCANB + 5000, 256, 0, stream>>>(indeg, loc, bsum, x, wlr, el1, er1);
  scan2_kernel<<<1, 128, 0, stream>>>(bsum, boff, rowptr + NN, NSCANB);
  pack_scatter_fin_kernel<<<NHISTB + NSCANB, 256, 0, stream>>>(src, dst, loc, boff, cursor,
                                                               csr_src, rowptr);

  // Layer 1 (x-space): aggregate x -> per-head GEMM with bias+ELU
  aggregate_x_kernel<<<NN, 128, 0, stream>>>(x, el1, er1, rowptr, csr_src, aggx);
  gemm64_kernel<128, true, true, false><<<dim3(313, 3), 128, 0, stream>>>(
      aggx, 384, W1, 384, h1, 384, b1, nullptr, nullptr, nullptr, nullptr);

  // Layer 2: f2 = h1 @ W2 (fused el2/er2 epilogue); aggregate(+b2) -> h2
  gemm64_kernel<384, false, false, true><<<dim3(313, 1), 128, 0, stream>>>(
      h1, 384, W2, 128, f2, 128, nullptr, al2, ar2, el2, er2);
  aggregate1_kernel<<<NN, 128, 0, stream>>>(f2, el2, er2, b2, rowptr, csr_src, h2);

  // mean-pool (2-stage) + linear head + relu
  pool_partial_kernel<<<NG * PSPLIT, 128, 0, stream>>>(h2, gid, gsums, NN);
  pool_final_kernel<<<NG, 128, 0, stream>>>(gsums, gid, linW, linb, out, NN);
}